// Round 4
// baseline (55.530 us; speedup 1.0000x reference)
//
#include <hip/hip_runtime.h>

// CrossNetwork: xl_{i+1} = x0 * dot(xl_i, W[i]) + b[i] + xl_i, CROSS=3.
// R4: barrier-free. One 64-lane wave owns a whole row (32 floats/thread);
// the dot reduction is a 6-step __shfl_xor butterfly (all lanes get s),
// so there is NO LDS and NO __syncthreads. 4 independent waves per
// 256-thread block. Plain stores (nt was neutral, R3).
// Memory-bound floor: 134 MB read + 134 MB write = 42.6 us at 6.29 TB/s.

constexpr int D_DIM    = 2048;
constexpr int NTHREADS = 256;
constexpr int CROSS    = 3;
constexpr int CHUNKS   = 8;   // float4s per lane: 2048/4/64

__global__ __launch_bounds__(NTHREADS, 4)
void cross_network_kernel(const float* __restrict__ x,
                          const float* __restrict__ W,
                          const float* __restrict__ bias,
                          float* __restrict__ out) {
    const int wave = threadIdx.x >> 6;
    const int lane = threadIdx.x & 63;
    const int row  = blockIdx.x * 4 + wave;

    const float4* xr = reinterpret_cast<const float4*>(x + (size_t)row * D_DIM);

    // Lane l owns float4 indices l + 64k, k = 0..7 (coalesced 1KB/instr).
    float4 x0[CHUNKS], xl[CHUNKS];
#pragma unroll
    for (int k = 0; k < CHUNKS; ++k) {
        x0[k] = xr[lane + 64 * k];
        xl[k] = x0[k];
    }

#pragma unroll
    for (int i = 0; i < CROSS; ++i) {
        const float4* wr = reinterpret_cast<const float4*>(W + i * D_DIM);
        float p = 0.0f;
#pragma unroll
        for (int k = 0; k < CHUNKS; ++k) {
            const float4 w = wr[lane + 64 * k];
            p = fmaf(xl[k].x, w.x, p);
            p = fmaf(xl[k].y, w.y, p);
            p = fmaf(xl[k].z, w.z, p);
            p = fmaf(xl[k].w, w.w, p);
        }
        // Wave-64 butterfly: every lane ends with the full row dot.
#pragma unroll
        for (int off = 1; off < 64; off <<= 1)
            p += __shfl_xor(p, off, 64);

        const float4* br = reinterpret_cast<const float4*>(bias + i * D_DIM);
#pragma unroll
        for (int k = 0; k < CHUNKS; ++k) {
            const float4 b = br[lane + 64 * k];
            xl[k].x = fmaf(x0[k].x, p, b.x + xl[k].x);
            xl[k].y = fmaf(x0[k].y, p, b.y + xl[k].y);
            xl[k].z = fmaf(x0[k].z, p, b.z + xl[k].z);
            xl[k].w = fmaf(x0[k].w, p, b.w + xl[k].w);
        }
    }

    float4* outr = reinterpret_cast<float4*>(out + (size_t)row * D_DIM);
#pragma unroll
    for (int k = 0; k < CHUNKS; ++k)
        outr[lane + 64 * k] = xl[k];
}

extern "C" void kernel_launch(void* const* d_in, const int* in_sizes, int n_in,
                              void* d_out, int out_size, void* d_ws, size_t ws_size,
                              hipStream_t stream) {
    const float* x    = (const float*)d_in[0];
    const float* W    = (const float*)d_in[1];
    const float* bias = (const float*)d_in[2];
    float* out = (float*)d_out;

    const int B = in_sizes[0] / D_DIM;     // 16384 rows
    const int blocks = B / 4;              // 4 rows (waves) per block
    cross_network_kernel<<<blocks, NTHREADS, 0, stream>>>(x, W, bias, out);
}

// Round 5
// 49.567 us; speedup vs baseline: 1.1203x; 1.1203x over previous
//
#include <hip/hip_runtime.h>

// CrossNetwork, algebraically flattened (R5):
//   d_i  = x . W_i                      (all three dots use ORIGINAL x)
//   s0 = d0
//   s1 = (1+s0)*d1 + (b0 . W1)
//   s2 = (1+s0+s1)*d2 + ((b0+b1) . W2)
//   out = x*(1+s0+s1+s2) + (b0+b1+b2)
// => single pass over x, 5 partial dots reduced in ONE shuffle+LDS round with
// ONE __syncthreads (R1 had 3 serial rounds). Block-per-row, 256 threads,
// low VGPR to keep the 76% occupancy that R4 proved is load-bearing.
// Memory floor: 134 MB read + 134 MB write ~= 42.6 us at 6.29 TB/s.

constexpr int D_DIM    = 2048;
constexpr int NTHREADS = 256;

__global__ __launch_bounds__(NTHREADS)
void cross_network_kernel(const float* __restrict__ x,
                          const float* __restrict__ W,
                          const float* __restrict__ bias,
                          float* __restrict__ out) {
    const int row  = blockIdx.x;
    const int t    = threadIdx.x;
    const int lane = t & 63;
    const int wave = t >> 6;

    // Thread t owns float4 elements t and t+256 of the 512-float4 row.
    const float4* xr = reinterpret_cast<const float4*>(x + (size_t)row * D_DIM);
    const float4 xa = xr[t];
    const float4 xb = xr[t + NTHREADS];

    const float4* w0r = reinterpret_cast<const float4*>(W);
    const float4* w1r = reinterpret_cast<const float4*>(W + D_DIM);
    const float4* w2r = reinterpret_cast<const float4*>(W + 2 * D_DIM);
    const float4* b0r = reinterpret_cast<const float4*>(bias);
    const float4* b1r = reinterpret_cast<const float4*>(bias + D_DIM);
    const float4* b2r = reinterpret_cast<const float4*>(bias + 2 * D_DIM);

    // b0, b1 stay live across the barrier (needed for bsum at the end).
    const float4 b0a = b0r[t], b0b = b0r[t + NTHREADS];
    const float4 b1a = b1r[t], b1b = b1r[t + NTHREADS];

    // 5 partial dots; W registers die immediately after use.
    float p0, p1, p2, q1, q2;
    {
        const float4 w0a = w0r[t], w0b = w0r[t + NTHREADS];
        p0 = xa.x*w0a.x + xa.y*w0a.y + xa.z*w0a.z + xa.w*w0a.w
           + xb.x*w0b.x + xb.y*w0b.y + xb.z*w0b.z + xb.w*w0b.w;
    }
    {
        const float4 w1a = w1r[t], w1b = w1r[t + NTHREADS];
        p1 = xa.x*w1a.x + xa.y*w1a.y + xa.z*w1a.z + xa.w*w1a.w
           + xb.x*w1b.x + xb.y*w1b.y + xb.z*w1b.z + xb.w*w1b.w;
        q1 = b0a.x*w1a.x + b0a.y*w1a.y + b0a.z*w1a.z + b0a.w*w1a.w
           + b0b.x*w1b.x + b0b.y*w1b.y + b0b.z*w1b.z + b0b.w*w1b.w;
    }
    {
        const float4 w2a = w2r[t], w2b = w2r[t + NTHREADS];
        p2 = xa.x*w2a.x + xa.y*w2a.y + xa.z*w2a.z + xa.w*w2a.w
           + xb.x*w2b.x + xb.y*w2b.y + xb.z*w2b.z + xb.w*w2b.w;
        q2 = (b0a.x+b1a.x)*w2a.x + (b0a.y+b1a.y)*w2a.y
           + (b0a.z+b1a.z)*w2a.z + (b0a.w+b1a.w)*w2a.w
           + (b0b.x+b1b.x)*w2b.x + (b0b.y+b1b.y)*w2b.y
           + (b0b.z+b1b.z)*w2b.z + (b0b.w+b1b.w)*w2b.w;
    }

    // One reduction round for all 5 scalars: wave butterfly + 4-wave LDS.
#pragma unroll
    for (int off = 32; off >= 1; off >>= 1) {
        p0 += __shfl_down(p0, off, 64);
        p1 += __shfl_down(p1, off, 64);
        p2 += __shfl_down(p2, off, 64);
        q1 += __shfl_down(q1, off, 64);
        q2 += __shfl_down(q2, off, 64);
    }

    __shared__ float sred[5][4];
    if (lane == 0) {
        sred[0][wave] = p0;
        sred[1][wave] = p1;
        sred[2][wave] = p2;
        sred[3][wave] = q1;
        sred[4][wave] = q2;
    }
    __syncthreads();

    const float d0  = sred[0][0] + sred[0][1] + sred[0][2] + sred[0][3];
    const float d1  = sred[1][0] + sred[1][1] + sred[1][2] + sred[1][3];
    const float d2  = sred[2][0] + sred[2][1] + sred[2][2] + sred[2][3];
    const float c01 = sred[3][0] + sred[3][1] + sred[3][2] + sred[3][3];
    const float c02 = sred[4][0] + sred[4][1] + sred[4][2] + sred[4][3];

    // Scalar recurrence (each thread redundantly, 6 flops).
    const float s0 = d0;
    const float t1 = 1.0f + s0;
    const float s1 = fmaf(t1, d1, c01);
    const float t2 = t1 + s1;
    const float s2 = fmaf(t2, d2, c02);
    const float scale = t2 + s2;   // 1 + s0 + s1 + s2

    // out = x*scale + (b0+b1+b2)
    const float4 b2a = b2r[t], b2b = b2r[t + NTHREADS];
    float4 oa, ob;
    oa.x = fmaf(xa.x, scale, b0a.x + b1a.x + b2a.x);
    oa.y = fmaf(xa.y, scale, b0a.y + b1a.y + b2a.y);
    oa.z = fmaf(xa.z, scale, b0a.z + b1a.z + b2a.z);
    oa.w = fmaf(xa.w, scale, b0a.w + b1a.w + b2a.w);
    ob.x = fmaf(xb.x, scale, b0b.x + b1b.x + b2b.x);
    ob.y = fmaf(xb.y, scale, b0b.y + b1b.y + b2b.y);
    ob.z = fmaf(xb.z, scale, b0b.z + b1b.z + b2b.z);
    ob.w = fmaf(xb.w, scale, b0b.w + b1b.w + b2b.w);

    float4* outr = reinterpret_cast<float4*>(out + (size_t)row * D_DIM);
    outr[t]            = oa;
    outr[t + NTHREADS] = ob;
}

extern "C" void kernel_launch(void* const* d_in, const int* in_sizes, int n_in,
                              void* d_out, int out_size, void* d_ws, size_t ws_size,
                              hipStream_t stream) {
    const float* x    = (const float*)d_in[0];
    const float* W    = (const float*)d_in[1];
    const float* bias = (const float*)d_in[2];
    float* out = (float*)d_out;

    const int B = in_sizes[0] / D_DIM;  // 16384
    cross_network_kernel<<<B, NTHREADS, 0, stream>>>(x, W, bias, out);
}

// Round 6
// 43.501 us; speedup vs baseline: 1.2765x; 1.1394x over previous
//
#include <hip/hip_runtime.h>

// CrossNetwork flattened (R6): out = x*scale + (b0+b1+b2), where
//   d_i = x.W_i ; c01 = b0.W1 ; c02 = (b0+b1).W2   (c01,c02 row-independent)
//   s0=d0; s1=(1+s0)d1+c01; s2=(1+s0+s1)d2+c02; scale=1+s0+s1+s2
// R6 change: ROWS=2 rows per 256-thread block to halve the W/b L2 re-read
// traffic (was 786 MB/dispatch across 16384 blocks; R1/R5 showed HBM at only
// 65% of copy ceiling -> L2/TCP contention is the suspected limiter).
// Live-register discipline: fold b0+b1 in place, keep VGPR <= 64 cliff.

constexpr int D_DIM    = 2048;
constexpr int NTHREADS = 256;
constexpr int ROWS     = 2;

__device__ __forceinline__ float dot8(const float4 a0, const float4 a1,
                                      const float4 b0, const float4 b1) {
    return a0.x*b0.x + a0.y*b0.y + a0.z*b0.z + a0.w*b0.w
         + a1.x*b1.x + a1.y*b1.y + a1.z*b1.z + a1.w*b1.w;
}

__global__ __launch_bounds__(NTHREADS)
void cross_network_kernel(const float* __restrict__ x,
                          const float* __restrict__ W,
                          const float* __restrict__ bias,
                          float* __restrict__ out) {
    const int row0 = blockIdx.x * ROWS;
    const int t    = threadIdx.x;
    const int lane = t & 63;
    const int wave = t >> 6;

    // Thread t owns float4 columns t and t+256 of each row.
    const float4* xr0 = reinterpret_cast<const float4*>(x + (size_t)row0 * D_DIM);
    const float4* xr1 = reinterpret_cast<const float4*>(x + (size_t)(row0 + 1) * D_DIM);
    const float4 x0a = xr0[t], x0b = xr0[t + NTHREADS];
    const float4 x1a = xr1[t], x1b = xr1[t + NTHREADS];

    const float4* w0r = reinterpret_cast<const float4*>(W);
    const float4* w1r = reinterpret_cast<const float4*>(W + D_DIM);
    const float4* w2r = reinterpret_cast<const float4*>(W + 2 * D_DIM);
    const float4* b0r = reinterpret_cast<const float4*>(bias);
    const float4* b1r = reinterpret_cast<const float4*>(bias + D_DIM);
    const float4* b2r = reinterpret_cast<const float4*>(bias + 2 * D_DIM);

    float p00, p01, p10, p11, p20, p21, q1, q2;
    float4 bsa, bsb;   // running b0 -> b0+b1 (live), small footprint
    {
        const float4 wa = w0r[t], wb = w0r[t + NTHREADS];
        p00 = dot8(x0a, x0b, wa, wb);
        p01 = dot8(x1a, x1b, wa, wb);
    }
    {
        const float4 wa = w1r[t], wb = w1r[t + NTHREADS];
        p10 = dot8(x0a, x0b, wa, wb);
        p11 = dot8(x1a, x1b, wa, wb);
        bsa = b0r[t]; bsb = b0r[t + NTHREADS];
        q1  = dot8(bsa, bsb, wa, wb);          // b0 . W1
    }
    {
        const float4 wa = w2r[t], wb = w2r[t + NTHREADS];
        p20 = dot8(x0a, x0b, wa, wb);
        p21 = dot8(x1a, x1b, wa, wb);
        const float4 b1a = b1r[t], b1b = b1r[t + NTHREADS];
        bsa.x += b1a.x; bsa.y += b1a.y; bsa.z += b1a.z; bsa.w += b1a.w;
        bsb.x += b1b.x; bsb.y += b1b.y; bsb.z += b1b.z; bsb.w += b1b.w;
        q2  = dot8(bsa, bsb, wa, wb);          // (b0+b1) . W2
    }

    // One reduction round for all 8 partials: wave butterfly + 4-wave LDS.
#pragma unroll
    for (int off = 32; off >= 1; off >>= 1) {
        p00 += __shfl_down(p00, off, 64);
        p01 += __shfl_down(p01, off, 64);
        p10 += __shfl_down(p10, off, 64);
        p11 += __shfl_down(p11, off, 64);
        p20 += __shfl_down(p20, off, 64);
        p21 += __shfl_down(p21, off, 64);
        q1  += __shfl_down(q1,  off, 64);
        q2  += __shfl_down(q2,  off, 64);
    }

    __shared__ float sred[8][4];
    if (lane == 0) {
        sred[0][wave] = p00; sred[1][wave] = p01;
        sred[2][wave] = p10; sred[3][wave] = p11;
        sred[4][wave] = p20; sred[5][wave] = p21;
        sred[6][wave] = q1;  sred[7][wave] = q2;
    }
    __syncthreads();

    float d[8];
#pragma unroll
    for (int k = 0; k < 8; ++k)
        d[k] = sred[k][0] + sred[k][1] + sred[k][2] + sred[k][3];
    const float c01 = d[6], c02 = d[7];

    float scale[ROWS];
#pragma unroll
    for (int r = 0; r < ROWS; ++r) {
        const float s0 = d[0 + r];
        const float t1 = 1.0f + s0;
        const float s1 = fmaf(t1, d[2 + r], c01);
        const float t2 = t1 + s1;
        const float s2 = fmaf(t2, d[4 + r], c02);
        scale[r] = t2 + s2;
    }

    // bsum = (b0+b1) + b2 ; out_r = x_r * scale_r + bsum
    {
        const float4 b2a = b2r[t], b2b = b2r[t + NTHREADS];
        bsa.x += b2a.x; bsa.y += b2a.y; bsa.z += b2a.z; bsa.w += b2a.w;
        bsb.x += b2b.x; bsb.y += b2b.y; bsb.z += b2b.z; bsb.w += b2b.w;
    }

    float4* o0 = reinterpret_cast<float4*>(out + (size_t)row0 * D_DIM);
    float4* o1 = reinterpret_cast<float4*>(out + (size_t)(row0 + 1) * D_DIM);
    float4 v;
    v.x = fmaf(x0a.x, scale[0], bsa.x); v.y = fmaf(x0a.y, scale[0], bsa.y);
    v.z = fmaf(x0a.z, scale[0], bsa.z); v.w = fmaf(x0a.w, scale[0], bsa.w);
    o0[t] = v;
    v.x = fmaf(x0b.x, scale[0], bsb.x); v.y = fmaf(x0b.y, scale[0], bsb.y);
    v.z = fmaf(x0b.z, scale[0], bsb.z); v.w = fmaf(x0b.w, scale[0], bsb.w);
    o0[t + NTHREADS] = v;
    v.x = fmaf(x1a.x, scale[1], bsa.x); v.y = fmaf(x1a.y, scale[1], bsa.y);
    v.z = fmaf(x1a.z, scale[1], bsa.z); v.w = fmaf(x1a.w, scale[1], bsa.w);
    o1[t] = v;
    v.x = fmaf(x1b.x, scale[1], bsb.x); v.y = fmaf(x1b.y, scale[1], bsb.y);
    v.z = fmaf(x1b.z, scale[1], bsb.z); v.w = fmaf(x1b.w, scale[1], bsb.w);
    o1[t + NTHREADS] = v;
}

extern "C" void kernel_launch(void* const* d_in, const int* in_sizes, int n_in,
                              void* d_out, int out_size, void* d_ws, size_t ws_size,
                              hipStream_t stream) {
    const float* x    = (const float*)d_in[0];
    const float* W    = (const float*)d_in[1];
    const float* bias = (const float*)d_in[2];
    float* out = (float*)d_out;

    const int B = in_sizes[0] / D_DIM;      // 16384
    cross_network_kernel<<<B / ROWS, NTHREADS, 0, stream>>>(x, W, bias, out);
}